// Round 1
// baseline (842.331 us; speedup 1.0000x reference)
//
#include <hip/hip_runtime.h>
#include <hip/hip_bf16.h>

#define F 128

typedef __attribute__((ext_vector_type(8))) short bf16x8;
typedef __attribute__((ext_vector_type(4))) float f32x4;

// ---------- helpers ----------

__device__ __forceinline__ short f2bf(float f) {
  union { float f; unsigned u; } v; v.f = f;
  unsigned r = (v.u + 0x7FFFu + ((v.u >> 16) & 1u)) >> 16;  // RNE
  return (short)r;
}

// shifted softplus: softplus(x) - ln(2), numerically stable
__device__ __forceinline__ float sspf(float x) {
  float t = __expf(-fabsf(x));
  return fmaxf(x, 0.0f) + __logf(1.0f + t) - 0.69314718055994530942f;
}

// H/C staging in LDS: 128 rows x 128 bf16, XOR-swizzled in 8-short (16B) chunks
// so that b16 scatter-writes and b128 A-frag reads are both ~conflict-free.
__device__ __forceinline__ int h_idx(int row, int k) {
  int chunk = k >> 3;
  int sw = chunk ^ (row & 15);
  return row * 128 + sw * 8 + (k & 7);
}

// wf staging: 128 rows x 128 f32, bit-4 XOR swizzle breaks the 4-quad conflict
__device__ __forceinline__ int wf_idx(int row, int c) {
  return row * 128 + (c ^ ((row & 4) << 2));
}

// B-fragment load from LDS frag-ordered weight: frag (nt,kb) is 64 lanes x 16B
__device__ __forceinline__ bf16x8 load_bfrag(const short* sW, int nt, int kb, int lane) {
  return *(const bf16x8*)(sW + (((nt * 4 + kb) * 64 + lane) << 3));
}

// A-fragment from row-major fp32 global: 8 consecutive floats -> 8 bf16
__device__ __forceinline__ bf16x8 load_afrag_f32(const float* __restrict__ p, bool valid) {
  bf16x8 a = {0, 0, 0, 0, 0, 0, 0, 0};
  if (valid) {
    const float4* q = (const float4*)p;
    float4 x0 = q[0], x1 = q[1];
    a[0] = f2bf(x0.x); a[1] = f2bf(x0.y); a[2] = f2bf(x0.z); a[3] = f2bf(x0.w);
    a[4] = f2bf(x1.x); a[5] = f2bf(x1.y); a[6] = f2bf(x1.z); a[7] = f2bf(x1.w);
  }
  return a;
}

// ---------- prep: convert 5 weight matrices to bf16 MFMA-B-fragment order ----------
// B-frag layout for W[k][n] (128x128): frag(nt,kb), lane = ((k>>3)&3)<<4 | (n&15), j = k&7
__global__ void prep_weights(const float* __restrict__ W1, const float* __restrict__ W2,
                             const float* __restrict__ Wi2f, const float* __restrict__ Wf2o,
                             const float* __restrict__ Wd, unsigned short* __restrict__ out) {
  int t = blockIdx.x * 256 + threadIdx.x;  // 5*16384 total
  int m = t >> 14;
  int idx = t & 16383;
  int k = idx >> 7, n = idx & 127;
  const float* W = (m == 0) ? W1 : (m == 1) ? W2 : (m == 2) ? Wi2f : (m == 3) ? Wf2o : Wd;
  float v = W[idx];
  int nt = n >> 4, kb = k >> 5;
  int lane = (((k >> 3) & 3) << 4) | (n & 15);
  int j = k & 7;
  int dst = (((nt * 4 + kb) * 64 + lane) << 3) | j;
  out[(m << 14) + dst] = (unsigned short)f2bf(v);
}

// ---------- f = x @ W_in2fac  (no bias, no activation) ----------
__global__ __launch_bounds__(256, 2) void f_kernel(const float* __restrict__ x,
                                                   const unsigned short* __restrict__ wfrag,
                                                   float* __restrict__ f, int N) {
  __shared__ union { short s[16384]; float4 v4[2048]; } sm;
  const int tid = threadIdx.x;
  const int lane = tid & 63, wv = tid >> 6;
  const int quad = lane >> 4, ln = lane & 15;
  const int r0 = blockIdx.x * 128;

  { // stage W_in2fac frags (32KB)
    const float4* src = (const float4*)(wfrag + 2 * 16384);
#pragma unroll
    for (int i = 0; i < 8; ++i) sm.v4[tid + 256 * i] = src[tid + 256 * i];
  }

  bf16x8 a1[2][4];
#pragma unroll
  for (int mt = 0; mt < 2; ++mt) {
    int row = r0 + wv * 32 + mt * 16 + ln;
    bool valid = row < N;
    const float* rp = x + (size_t)row * F + quad * 8;
#pragma unroll
    for (int kb = 0; kb < 4; ++kb) a1[mt][kb] = load_afrag_f32(rp + kb * 32, valid);
  }
  __syncthreads();

#pragma unroll
  for (int nt = 0; nt < 8; ++nt) {
    f32x4 acc0 = {0, 0, 0, 0}, acc1 = {0, 0, 0, 0};
#pragma unroll
    for (int kb = 0; kb < 4; ++kb) {
      bf16x8 b = load_bfrag(sm.s, nt, kb, lane);
      acc0 = __builtin_amdgcn_mfma_f32_16x16x32_bf16(a1[0][kb], b, acc0, 0, 0, 0);
      acc1 = __builtin_amdgcn_mfma_f32_16x16x32_bf16(a1[1][kb], b, acc1, 0, 0, 0);
    }
    int col = nt * 16 + ln;
#pragma unroll
    for (int mt = 0; mt < 2; ++mt) {
#pragma unroll
      for (int r = 0; r < 4; ++r) {
        int row = r0 + wv * 32 + mt * 16 + quad * 4 + r;
        if (row < N) f[(size_t)row * F + col] = (mt == 0) ? acc0[r] : acc1[r];
      }
    }
  }
}

// ---------- fused edge pipeline ----------
// h = ssp(dijk@W1+b1); w = ssp(h@W2+b2); (seg_j = arange -> identity)
// wf = w * f[idx_j]; conv[seg_i] += wf  (seg_i sorted -> run-length reduce + atomics)
__global__ __launch_bounds__(256, 2) void edge_kernel(
    const float* __restrict__ dijk, const int* __restrict__ idx_j, const int* __restrict__ seg_i,
    const float* __restrict__ b1, const float* __restrict__ b2,
    const unsigned short* __restrict__ wfrag, const float* __restrict__ f,
    float* __restrict__ conv, int E) {
  // 64KB aliased: ph1 [0,32KB)=W1frags [32KB,64KB)=W2frags; ph2 [0,32KB)=H-staging;
  // ph3 whole 64KB = wf tile (f32)
  __shared__ union { short s[32768]; float fl[16384]; float4 v4[4096]; } sm;
  __shared__ int sIdx[128];
  __shared__ int sSeg[128];

  const int tid = threadIdx.x;
  const int lane = tid & 63, wv = tid >> 6;
  const int quad = lane >> 4, ln = lane & 15;
  const int e0 = blockIdx.x * 128;

  { // stage W1+W2 frags (64KB)
    const float4* src = (const float4*)wfrag;
#pragma unroll
    for (int i = 0; i < 16; ++i) sm.v4[tid + 256 * i] = src[tid + 256 * i];
  }
  if (tid < 128) {
    int e = e0 + tid;
    sIdx[tid] = (e < E) ? idx_j[e] : 0;
    sSeg[tid] = (e < E) ? seg_i[e] : -1;
  }

  float bias1v[8], bias2v[8];
#pragma unroll
  for (int nt = 0; nt < 8; ++nt) {
    bias1v[nt] = b1[nt * 16 + ln];
    bias2v[nt] = b2[nt * 16 + ln];
  }

  // A1 frags straight from global dijk (each wave owns 32 edge rows)
  bf16x8 a1[2][4];
#pragma unroll
  for (int mt = 0; mt < 2; ++mt) {
    int row = e0 + wv * 32 + mt * 16 + ln;
    bool valid = row < E;
    const float* rp = dijk + (size_t)row * F + quad * 8;
#pragma unroll
    for (int kb = 0; kb < 4; ++kb) a1[mt][kb] = load_afrag_f32(rp + kb * 32, valid);
  }
  __syncthreads();

  // GEMM1 -> h (bf16, kept in regs)
  short hreg[2][8][4];
  const short* sW1 = sm.s;
  const short* sW2 = sm.s + 16384;
#pragma unroll
  for (int nt = 0; nt < 8; ++nt) {
    f32x4 acc0 = {0, 0, 0, 0}, acc1 = {0, 0, 0, 0};
#pragma unroll
    for (int kb = 0; kb < 4; ++kb) {
      bf16x8 b = load_bfrag(sW1, nt, kb, lane);
      acc0 = __builtin_amdgcn_mfma_f32_16x16x32_bf16(a1[0][kb], b, acc0, 0, 0, 0);
      acc1 = __builtin_amdgcn_mfma_f32_16x16x32_bf16(a1[1][kb], b, acc1, 0, 0, 0);
    }
#pragma unroll
    for (int r = 0; r < 4; ++r) {
      hreg[0][nt][r] = f2bf(sspf(acc0[r] + bias1v[nt]));
      hreg[1][nt][r] = f2bf(sspf(acc1[r] + bias1v[nt]));
    }
  }
  __syncthreads();  // everyone done reading W1 region

  // stage H (C-layout regs -> swizzled LDS) for the GEMM2 A-operand transpose
  short* sH = sm.s;
#pragma unroll
  for (int mt = 0; mt < 2; ++mt)
#pragma unroll
    for (int nt = 0; nt < 8; ++nt)
#pragma unroll
      for (int r = 0; r < 4; ++r) {
        int row = wv * 32 + mt * 16 + quad * 4 + r;
        sH[h_idx(row, nt * 16 + ln)] = hreg[mt][nt][r];
      }
  __syncthreads();

  // GEMM2 A frags from staged H
  bf16x8 a2[2][4];
#pragma unroll
  for (int mt = 0; mt < 2; ++mt) {
    int row = wv * 32 + mt * 16 + ln;
#pragma unroll
    for (int kb = 0; kb < 4; ++kb)
      a2[mt][kb] = *(const bf16x8*)(sH + h_idx(row, kb * 32 + quad * 8));
  }

  float wreg[2][8][4];
#pragma unroll
  for (int nt = 0; nt < 8; ++nt) {
    f32x4 acc0 = {0, 0, 0, 0}, acc1 = {0, 0, 0, 0};
#pragma unroll
    for (int kb = 0; kb < 4; ++kb) {
      bf16x8 b = load_bfrag(sW2, nt, kb, lane);
      acc0 = __builtin_amdgcn_mfma_f32_16x16x32_bf16(a2[0][kb], b, acc0, 0, 0, 0);
      acc1 = __builtin_amdgcn_mfma_f32_16x16x32_bf16(a2[1][kb], b, acc1, 0, 0, 0);
    }
#pragma unroll
    for (int r = 0; r < 4; ++r) {
      wreg[0][nt][r] = sspf(acc0[r] + bias2v[nt]);
      wreg[1][nt][r] = sspf(acc1[r] + bias2v[nt]);
    }
  }
  __syncthreads();  // everyone done reading sH + W2 before wf overwrites all 64KB

  // wf = w * f[idx_j]  -> swizzled LDS tile
  float* sWF = sm.fl;
#pragma unroll
  for (int mt = 0; mt < 2; ++mt)
#pragma unroll
    for (int r = 0; r < 4; ++r) {
      int rloc = wv * 32 + mt * 16 + quad * 4 + r;
      int jrow = sIdx[rloc];
      const float* fp = f + (size_t)jrow * F;
#pragma unroll
      for (int nt = 0; nt < 8; ++nt) {
        int c = nt * 16 + ln;
        sWF[wf_idx(rloc, c)] = wreg[mt][nt][r] * fp[c];
      }
    }
  __syncthreads();

  // segmented reduction over sorted seg_i: run-length accumulate, one atomic per run
  {
    int c = tid & 127;
    int half = tid >> 7;
    int r0 = half * 64;
    float acc = 0.0f;
    int cur = sSeg[r0];
    for (int r = r0; r < r0 + 64; ++r) {
      int s = sSeg[r];
      if (s != cur) {
        if (cur >= 0) atomicAdd(conv + (size_t)cur * F + c, acc);
        acc = 0.0f; cur = s;
      }
      acc += sWF[wf_idx(r, c)];
    }
    if (cur >= 0) atomicAdd(conv + (size_t)cur * F + c, acc);
  }
}

// ---------- node pipeline: c = ssp(conv@Wf2o + b); v = c@Wd + b; y = x + v ----------
__global__ __launch_bounds__(256, 2) void node_kernel(
    const float* __restrict__ conv, const float* __restrict__ x,
    const float* __restrict__ bf2o, const float* __restrict__ bd,
    const unsigned short* __restrict__ wfrag, float* __restrict__ y,
    float* __restrict__ vout, int N) {
  __shared__ union { short s[32768]; float4 v4[4096]; } sm;
  const int tid = threadIdx.x;
  const int lane = tid & 63, wv = tid >> 6;
  const int quad = lane >> 4, ln = lane & 15;
  const int r0 = blockIdx.x * 128;

  { // Wf2o frags -> [0,32KB), Wd frags -> [32KB,64KB)
    const float4* src = (const float4*)(wfrag + 3 * 16384);
#pragma unroll
    for (int i = 0; i < 16; ++i) sm.v4[tid + 256 * i] = src[tid + 256 * i];
  }

  float bfv[8], bdv[8];
#pragma unroll
  for (int nt = 0; nt < 8; ++nt) {
    bfv[nt] = bf2o[nt * 16 + ln];
    bdv[nt] = bd[nt * 16 + ln];
  }

  bf16x8 a1[2][4];
#pragma unroll
  for (int mt = 0; mt < 2; ++mt) {
    int row = r0 + wv * 32 + mt * 16 + ln;
    bool valid = row < N;
    const float* rp = conv + (size_t)row * F + quad * 8;
#pragma unroll
    for (int kb = 0; kb < 4; ++kb) a1[mt][kb] = load_afrag_f32(rp + kb * 32, valid);
  }
  __syncthreads();

  short creg[2][8][4];
  const short* sWa = sm.s;
  const short* sWd = sm.s + 16384;
#pragma unroll
  for (int nt = 0; nt < 8; ++nt) {
    f32x4 acc0 = {0, 0, 0, 0}, acc1 = {0, 0, 0, 0};
#pragma unroll
    for (int kb = 0; kb < 4; ++kb) {
      bf16x8 b = load_bfrag(sWa, nt, kb, lane);
      acc0 = __builtin_amdgcn_mfma_f32_16x16x32_bf16(a1[0][kb], b, acc0, 0, 0, 0);
      acc1 = __builtin_amdgcn_mfma_f32_16x16x32_bf16(a1[1][kb], b, acc1, 0, 0, 0);
    }
#pragma unroll
    for (int r = 0; r < 4; ++r) {
      creg[0][nt][r] = f2bf(sspf(acc0[r] + bfv[nt]));
      creg[1][nt][r] = f2bf(sspf(acc1[r] + bfv[nt]));
    }
  }
  __syncthreads();

  short* sC = sm.s;
#pragma unroll
  for (int mt = 0; mt < 2; ++mt)
#pragma unroll
    for (int nt = 0; nt < 8; ++nt)
#pragma unroll
      for (int r = 0; r < 4; ++r) {
        int row = wv * 32 + mt * 16 + quad * 4 + r;
        sC[h_idx(row, nt * 16 + ln)] = creg[mt][nt][r];
      }
  __syncthreads();

  bf16x8 a2[2][4];
#pragma unroll
  for (int mt = 0; mt < 2; ++mt) {
    int row = wv * 32 + mt * 16 + ln;
#pragma unroll
    for (int kb = 0; kb < 4; ++kb)
      a2[mt][kb] = *(const bf16x8*)(sC + h_idx(row, kb * 32 + quad * 8));
  }

#pragma unroll
  for (int nt = 0; nt < 8; ++nt) {
    f32x4 acc0 = {0, 0, 0, 0}, acc1 = {0, 0, 0, 0};
#pragma unroll
    for (int kb = 0; kb < 4; ++kb) {
      bf16x8 b = load_bfrag(sWd, nt, kb, lane);
      acc0 = __builtin_amdgcn_mfma_f32_16x16x32_bf16(a2[0][kb], b, acc0, 0, 0, 0);
      acc1 = __builtin_amdgcn_mfma_f32_16x16x32_bf16(a2[1][kb], b, acc1, 0, 0, 0);
    }
    int col = nt * 16 + ln;
#pragma unroll
    for (int mt = 0; mt < 2; ++mt) {
#pragma unroll
      for (int r = 0; r < 4; ++r) {
        int row = r0 + wv * 32 + mt * 16 + quad * 4 + r;
        if (row < N) {
          float v = ((mt == 0) ? acc0[r] : acc1[r]) + bdv[nt];
          size_t o = (size_t)row * F + col;
          y[o] = x[o] + v;
          vout[o] = v;
        }
      }
    }
  }
}

extern "C" void kernel_launch(void* const* d_in, const int* in_sizes, int n_in,
                              void* d_out, int out_size, void* d_ws, size_t ws_size,
                              hipStream_t stream) {
  const float* x    = (const float*)d_in[0];
  const float* dijk = (const float*)d_in[1];
  const int*   idxj = (const int*)d_in[2];
  const int*   segi = (const int*)d_in[3];
  // d_in[4] = seg_j (identity permutation: segment_sum over it is a no-op)
  // d_in[5] = seg_i_sum (== N)
  const float* W1   = (const float*)d_in[6];
  const float* b1   = (const float*)d_in[7];
  const float* W2   = (const float*)d_in[8];
  const float* b2   = (const float*)d_in[9];
  const float* Wi2f = (const float*)d_in[10];
  const float* Wf2o = (const float*)d_in[11];
  const float* bf2o = (const float*)d_in[12];
  const float* Wd   = (const float*)d_in[13];
  const float* bd   = (const float*)d_in[14];

  int N = in_sizes[0] / F;
  int E = in_sizes[1] / F;

  // workspace layout: [5x16384 bf16 weight frags][f: N*F f32][conv: N*F f32]  (~51.4MB)
  unsigned short* wfrag = (unsigned short*)d_ws;
  float* fbuf = (float*)((char*)d_ws + 5 * 16384 * sizeof(unsigned short));
  float* conv = fbuf + (size_t)N * F;

  float* y = (float*)d_out;
  float* vout = y + (size_t)N * F;

  hipMemsetAsync(conv, 0, (size_t)N * F * sizeof(float), stream);
  prep_weights<<<320, 256, 0, stream>>>(W1, W2, Wi2f, Wf2o, Wd, wfrag);

  int nb = (N + 127) / 128;
  int eb = (E + 127) / 128;
  f_kernel<<<nb, 256, 0, stream>>>(x, wfrag, fbuf, N);
  edge_kernel<<<eb, 256, 0, stream>>>(dijk, idxj, segi, b1, b2, wfrag, fbuf, conv, E);
  node_kernel<<<nb, 256, 0, stream>>>(conv, x, bf2o, bd, wfrag, y, vout, N);
}